// Round 1
// baseline (2138.210 us; speedup 1.0000x reference)
//
#include <hip/hip_runtime.h>
#include <cstddef>
#include <cstdint>

#define NN   100000   // nodes
#define NR   4        // relations
#define NE   160000   // edges per relation
#define FIN  128
#define FHID 128
#define FOUT 64

// ---------------------------------------------------------------- helpers
__device__ __forceinline__ void fma4v(float4& a, const float4& w, float s) {
  a.x = fmaf(w.x, s, a.x);
  a.y = fmaf(w.y, s, a.y);
  a.z = fmaf(w.z, s, a.z);
  a.w = fmaf(w.w, s, a.w);
}

// ---------------------------------------------------------------- degrees
// deg layout: [0..NR*NN) = deg_out (by src), [NR*NN..2*NR*NN) = deg_in (by dst)
__global__ __launch_bounds__(256) void deg_count_k(const int* __restrict__ edges,
                                                   float* __restrict__ deg) {
  const int r = blockIdx.y;
  const int e = blockIdx.x * 256 + threadIdx.x;
  if (e >= NE) return;
  const int s = edges[(size_t)r * 2 * NE + e];
  const int d = edges[(size_t)r * 2 * NE + NE + e];
  unsafeAtomicAdd(&deg[(size_t)r * NN + s], 1.0f);
  unsafeAtomicAdd(&deg[(size_t)(NR + r) * NN + d], 1.0f);
}

__global__ __launch_bounds__(256) void rsq_k(float* __restrict__ v, int n) {
  const int i = blockIdx.x * 256 + threadIdx.x;
  if (i < n) v[i] = rsqrtf(fmaxf(v[i], 1.0f));
}

// ---------------------------------------------------------------- bias init
// acc[n][f] = sum_r b[r][f]   (bias is added for every node, every relation)
template <int F>
__global__ __launch_bounds__(256) void init_bias_k(float4* __restrict__ acc,
                                                   const float4* __restrict__ b,
                                                   int nvec) {
  const int i = blockIdx.x * 256 + threadIdx.x;
  if (i >= nvec) return;
  constexpr int C = F / 4;
  const int c = i & (C - 1);
  const float4 v0 = b[c];
  const float4 v1 = b[C + c];
  const float4 v2 = b[2 * C + c];
  const float4 v3 = b[3 * C + c];
  float4 s;
  s.x = v0.x + v1.x + v2.x + v3.x;
  s.y = v0.y + v1.y + v2.y + v3.y;
  s.z = v0.z + v1.z + v2.z + v3.z;
  s.w = v0.w + v1.w + v2.w + v3.w;
  acc[i] = s;
}

__global__ __launch_bounds__(256) void relu4_k(float4* __restrict__ v, int n) {
  const int i = blockIdx.x * 256 + threadIdx.x;
  if (i >= n) return;
  float4 a = v[i];
  a.x = fmaxf(a.x, 0.f);
  a.y = fmaxf(a.y, 0.f);
  a.z = fmaxf(a.z, 0.f);
  a.w = fmaxf(a.w, 0.f);
  v[i] = a;
}

// ---------------------------------------------------------------- GEMM
// H[n][j] = rs[n] * sum_k X[n][k] * W[k][j]      (K = 128 fixed)
// Block tile: 64 rows x 64 cols, 256 threads, per-thread 4x4.
// LDS: W tile 128x64 f32 (32KB) + X tile 64x32 float4 (32KB, XOR-swizzled).
template <int NOUT>
__global__ __launch_bounds__(256) void gemm_rs_k(const float* __restrict__ X,
                                                 const float* __restrict__ W,
                                                 const float* __restrict__ rs,
                                                 float* __restrict__ H, int M) {
  extern __shared__ float smem[];
  float*  Wl = smem;                       // [128][64]
  float4* X4 = (float4*)(smem + 128 * 64); // [64][32] float4, swizzled

  const int t    = threadIdx.x;
  const int row0 = blockIdx.x * 64;
  const int col0 = blockIdx.y * 64;

  // load W tile (contiguous float4 within rows of 64)
#pragma unroll
  for (int i = 0; i < 8; ++i) {
    const int fi = t + i * 256;       // float4 index in tile
    const int k  = fi >> 4;           // 16 float4 per row
    const int j4 = (fi & 15) << 2;
    *(float4*)&Wl[k * 64 + j4] = *(const float4*)&W[(size_t)k * NOUT + col0 + j4];
  }
  // load X tile, swizzled: cell(r,q) stored at r*32 + (q ^ ((r>>2)&7))
#pragma unroll
  for (int i = 0; i < 8; ++i) {
    const int fi = t + i * 256;
    const int rr = fi >> 5;           // 32 float4 per row
    const int q  = fi & 31;
    if (row0 + rr < M)
      X4[rr * 32 + (q ^ ((rr >> 2) & 7))] =
          *(const float4*)&X[(size_t)(row0 + rr) * 128 + q * 4];
  }
  __syncthreads();

  const int c   = (t & 15) << 2;   // 4 cols
  const int rg  = (t >> 4) << 2;   // 4 rows
  const int xsw = (t >> 4) & 7;    // swizzle key (constant over this thread's 4 rows)

  float4 a0 = {0, 0, 0, 0}, a1 = a0, a2 = a0, a3 = a0;

#pragma unroll 4
  for (int k0 = 0; k0 < 128; k0 += 4) {
    const float4 w0 = *(const float4*)&Wl[(k0 + 0) * 64 + c];
    const float4 w1 = *(const float4*)&Wl[(k0 + 1) * 64 + c];
    const float4 w2 = *(const float4*)&Wl[(k0 + 2) * 64 + c];
    const float4 w3 = *(const float4*)&Wl[(k0 + 3) * 64 + c];
    const int q = (k0 >> 2) ^ xsw;
    const float4 x0 = X4[(rg + 0) * 32 + q];
    const float4 x1 = X4[(rg + 1) * 32 + q];
    const float4 x2 = X4[(rg + 2) * 32 + q];
    const float4 x3 = X4[(rg + 3) * 32 + q];
    fma4v(a0, w0, x0.x); fma4v(a0, w1, x0.y); fma4v(a0, w2, x0.z); fma4v(a0, w3, x0.w);
    fma4v(a1, w0, x1.x); fma4v(a1, w1, x1.y); fma4v(a1, w2, x1.z); fma4v(a1, w3, x1.w);
    fma4v(a2, w0, x2.x); fma4v(a2, w1, x2.y); fma4v(a2, w2, x2.z); fma4v(a2, w3, x2.w);
    fma4v(a3, w0, x3.x); fma4v(a3, w1, x3.y); fma4v(a3, w2, x3.z); fma4v(a3, w3, x3.w);
  }

  const int rowb = row0 + rg;
  if (rowb + 0 < M) {
    const float s = rs[rowb + 0];
    float4 o; o.x = a0.x * s; o.y = a0.y * s; o.z = a0.z * s; o.w = a0.w * s;
    *(float4*)&H[(size_t)(rowb + 0) * NOUT + col0 + c] = o;
  }
  if (rowb + 1 < M) {
    const float s = rs[rowb + 1];
    float4 o; o.x = a1.x * s; o.y = a1.y * s; o.z = a1.z * s; o.w = a1.w * s;
    *(float4*)&H[(size_t)(rowb + 1) * NOUT + col0 + c] = o;
  }
  if (rowb + 2 < M) {
    const float s = rs[rowb + 2];
    float4 o; o.x = a2.x * s; o.y = a2.y * s; o.z = a2.z * s; o.w = a2.w * s;
    *(float4*)&H[(size_t)(rowb + 2) * NOUT + col0 + c] = o;
  }
  if (rowb + 3 < M) {
    const float s = rs[rowb + 3];
    float4 o; o.x = a3.x * s; o.y = a3.y * s; o.z = a3.z * s; o.w = a3.w * s;
    *(float4*)&H[(size_t)(rowb + 3) * NOUT + col0 + c] = o;
  }
}

// ---------------------------------------------------------------- scatter
// acc[dst[e]][f] += H[src[e]][f] * rs_in[dst[e]]
template <int F>
__global__ __launch_bounds__(256) void scatter_add_k(const float* __restrict__ H,
                                                     const int* __restrict__ src,
                                                     const int* __restrict__ dst,
                                                     const float* __restrict__ rsin,
                                                     float* __restrict__ acc) {
  constexpr int C = F / 4;
  const int i = blockIdx.x * 256 + threadIdx.x;
  const int e = i / C;
  const int c = i - e * C;
  if (e >= NE) return;
  const int s = src[e];
  const int d = dst[e];
  const float sc = rsin[d];
  const float4 v = *(const float4*)&H[(size_t)s * F + c * 4];
  float* ap = &acc[(size_t)d * F + c * 4];
  unsafeAtomicAdd(ap + 0, v.x * sc);
  unsafeAtomicAdd(ap + 1, v.y * sc);
  unsafeAtomicAdd(ap + 2, v.z * sc);
  unsafeAtomicAdd(ap + 3, v.w * sc);
}

// ---------------------------------------------------------------- launch
extern "C" void kernel_launch(void* const* d_in, const int* in_sizes, int n_in,
                              void* d_out, int out_size, void* d_ws, size_t ws_size,
                              hipStream_t stream) {
  const float* x     = (const float*)d_in[0];
  const int*   edges = (const int*)d_in[1];
  const float* W1    = (const float*)d_in[2];
  const float* b1    = (const float*)d_in[3];
  const float* W2    = (const float*)d_in[4];
  const float* b2    = (const float*)d_in[5];
  float* out = (float*)d_out;

  // workspace: rs_out[NR*NN] | rs_in[NR*NN] | hbuf[NN*128] | acc1[NN*128]  (~106 MB)
  float* rs_out = (float*)d_ws;
  float* rs_in  = rs_out + (size_t)NR * NN;
  float* hbuf   = rs_in  + (size_t)NR * NN;
  float* acc1   = hbuf   + (size_t)NN * FHID;

  // degrees (shared by both layers; same edge lists)
  hipMemsetAsync(rs_out, 0, (size_t)2 * NR * NN * sizeof(float), stream);
  deg_count_k<<<dim3((NE + 255) / 256, NR), 256, 0, stream>>>(edges, rs_out);
  const int ndeg = 2 * NR * NN;
  rsq_k<<<(ndeg + 255) / 256, 256, 0, stream>>>(rs_out, ndeg);

  // ---- layer 1: acc1 = sum_r [ scatter_r( rs_out_r * (x @ W1_r) ) * rs_in_r ] + sum_r b1_r
  init_bias_k<FHID><<<((NN * FHID / 4) + 255) / 256, 256, 0, stream>>>(
      (float4*)acc1, (const float4*)b1, NN * FHID / 4);
  for (int r = 0; r < NR; ++r) {
    gemm_rs_k<FHID><<<dim3((NN + 63) / 64, FHID / 64), 256, 65536, stream>>>(
        x, W1 + (size_t)r * FIN * FHID, rs_out + (size_t)r * NN, hbuf, NN);
    scatter_add_k<FHID><<<(NE * (FHID / 4)) / 256, 256, 0, stream>>>(
        hbuf, edges + (size_t)r * 2 * NE, edges + (size_t)r * 2 * NE + NE,
        rs_in + (size_t)r * NN, acc1);
  }
  relu4_k<<<((NN * FHID / 4) + 255) / 256, 256, 0, stream>>>((float4*)acc1, NN * FHID / 4);

  // ---- layer 2: out = sum_r [ scatter_r( rs_out_r * (h1 @ W2_r) ) * rs_in_r ] + sum_r b2_r
  init_bias_k<FOUT><<<((NN * FOUT / 4) + 255) / 256, 256, 0, stream>>>(
      (float4*)out, (const float4*)b2, NN * FOUT / 4);
  for (int r = 0; r < NR; ++r) {
    gemm_rs_k<FOUT><<<dim3((NN + 63) / 64, FOUT / 64), 256, 65536, stream>>>(
        acc1, W2 + (size_t)r * FHID * FOUT, rs_out + (size_t)r * NN, hbuf, NN);
    scatter_add_k<FOUT><<<(NE * (FOUT / 4)) / 256, 256, 0, stream>>>(
        hbuf, edges + (size_t)r * 2 * NE, edges + (size_t)r * 2 * NE + NE,
        rs_in + (size_t)r * NN, out);
  }
}

// Round 2
// 765.715 us; speedup vs baseline: 2.7924x; 2.7924x over previous
//
#include <hip/hip_runtime.h>
#include <cstddef>
#include <cstdint>

#define NN   100000   // nodes
#define NR   4        // relations
#define NE   160000   // edges per relation
#define FIN  128
#define FHID 128
#define FOUT 64
#define SCAN_B 1024   // elements per scan block

// ---------------------------------------------------------------- helpers
__device__ __forceinline__ void fma4v(float4& a, const float4& w, float s) {
  a.x = fmaf(w.x, s, a.x);
  a.y = fmaf(w.y, s, a.y);
  a.z = fmaf(w.z, s, a.z);
  a.w = fmaf(w.w, s, a.w);
}

// ---------------------------------------------------------------- degree counts (int)
__global__ __launch_bounds__(256) void count_k(const int* __restrict__ edges,
                                               int* __restrict__ cnt_out,
                                               int* __restrict__ cnt_in) {
  const int r = blockIdx.y;
  const int e = blockIdx.x * 256 + threadIdx.x;
  if (e >= NE) return;
  const int s = edges[(size_t)r * 2 * NE + e];
  const int d = edges[(size_t)r * 2 * NE + NE + e];
  atomicAdd(&cnt_out[(size_t)r * NN + s], 1);
  atomicAdd(&cnt_in[(size_t)r * NN + d], 1);
}

// rs[i] = rsqrt(max(cnt[i],1))
__global__ __launch_bounds__(256) void rs_k(const int* __restrict__ cnt,
                                            float* __restrict__ rs, int n) {
  const int i = blockIdx.x * 256 + threadIdx.x;
  if (i < n) rs[i] = rsqrtf(fmaxf((float)cnt[i], 1.0f));
}

// ---------------------------------------------------------------- prefix scan (CSR row_ptr)
// scan1: per-block exclusive scan of cnt_in -> tmp (cursor used as temp), block totals -> bsum[r][128]
__global__ __launch_bounds__(256) void scan1_k(const int* __restrict__ cnt,
                                               int* __restrict__ excl,
                                               int* __restrict__ bsum, int n) {
  const int r = blockIdx.y, b = blockIdx.x, t = threadIdx.x;
  const int base = b * SCAN_B;
  int v[4]; int tl = 0;
#pragma unroll
  for (int i = 0; i < 4; ++i) {
    const int idx = base + t * 4 + i;
    v[i] = (idx < n) ? cnt[(size_t)r * n + idx] : 0;
    tl += v[i];
  }
  __shared__ int sm[256];
  sm[t] = tl;
  __syncthreads();
  for (int off = 1; off < 256; off <<= 1) {
    const int x = (t >= off) ? sm[t - off] : 0;
    __syncthreads();
    sm[t] += x;
    __syncthreads();
  }
  const int incl = sm[t];
  int run = incl - tl;  // exclusive
#pragma unroll
  for (int i = 0; i < 4; ++i) {
    const int idx = base + t * 4 + i;
    if (idx < n) excl[(size_t)r * n + idx] = run;
    run += v[i];
  }
  if (t == 255) bsum[r * 128 + b] = incl;
}

// scan2: exclusive scan of block totals (one block per relation, nb<=128)
__global__ __launch_bounds__(128) void scan2_k(int* __restrict__ bsum, int nb) {
  const int r = blockIdx.x, t = threadIdx.x;
  __shared__ int sm[128];
  const int v = (t < nb) ? bsum[r * 128 + t] : 0;
  sm[t] = v;
  __syncthreads();
  for (int off = 1; off < 128; off <<= 1) {
    const int x = (t >= off) ? sm[t - off] : 0;
    __syncthreads();
    sm[t] += x;
    __syncthreads();
  }
  if (t < nb) bsum[r * 128 + t] = sm[t] - v;  // exclusive
}

// scan3: add block offsets -> row_ptr (stride NN+1) and cursor copy
__global__ __launch_bounds__(256) void scan3_k(const int* __restrict__ excl,
                                               const int* __restrict__ bsum,
                                               int* __restrict__ row_ptr,
                                               int* __restrict__ cursor, int n) {
  const int r = blockIdx.y;
  const int i = blockIdx.x * 256 + threadIdx.x;
  if (i < n) {
    const int v = excl[(size_t)r * n + i] + bsum[r * 128 + i / SCAN_B];
    row_ptr[(size_t)r * (n + 1) + i] = v;
    cursor[(size_t)r * n + i] = v;
  }
  if (i == 0) row_ptr[(size_t)r * (n + 1) + n] = NE;
}

// fill: csr_src[r][pos] = src, pos from per-dst cursor
__global__ __launch_bounds__(256) void fill_k(const int* __restrict__ edges,
                                              int* __restrict__ cursor,
                                              int* __restrict__ csr) {
  const int r = blockIdx.y;
  const int e = blockIdx.x * 256 + threadIdx.x;
  if (e >= NE) return;
  const int s = edges[(size_t)r * 2 * NE + e];
  const int d = edges[(size_t)r * 2 * NE + NE + e];
  const int pos = atomicAdd(&cursor[(size_t)r * NN + d], 1);
  csr[(size_t)r * NE + pos] = s;
}

// ---------------------------------------------------------------- bias init
template <int F>
__global__ __launch_bounds__(256) void init_bias_k(float4* __restrict__ acc,
                                                   const float4* __restrict__ b,
                                                   int nvec) {
  const int i = blockIdx.x * 256 + threadIdx.x;
  if (i >= nvec) return;
  constexpr int C = F / 4;
  const int c = i & (C - 1);
  const float4 v0 = b[c];
  const float4 v1 = b[C + c];
  const float4 v2 = b[2 * C + c];
  const float4 v3 = b[3 * C + c];
  float4 s;
  s.x = v0.x + v1.x + v2.x + v3.x;
  s.y = v0.y + v1.y + v2.y + v3.y;
  s.z = v0.z + v1.z + v2.z + v3.z;
  s.w = v0.w + v1.w + v2.w + v3.w;
  acc[i] = s;
}

__global__ __launch_bounds__(256) void relu4_k(float4* __restrict__ v, int n) {
  const int i = blockIdx.x * 256 + threadIdx.x;
  if (i >= n) return;
  float4 a = v[i];
  a.x = fmaxf(a.x, 0.f);
  a.y = fmaxf(a.y, 0.f);
  a.z = fmaxf(a.z, 0.f);
  a.w = fmaxf(a.w, 0.f);
  v[i] = a;
}

// ---------------------------------------------------------------- GEMM
// H[n][j] = rs[n] * sum_k X[n][k] * W[k][j]      (K = 128 fixed)
template <int NOUT>
__global__ __launch_bounds__(256) void gemm_rs_k(const float* __restrict__ X,
                                                 const float* __restrict__ W,
                                                 const float* __restrict__ rs,
                                                 float* __restrict__ H, int M) {
  extern __shared__ float smem[];
  float*  Wl = smem;                       // [128][64]
  float4* X4 = (float4*)(smem + 128 * 64); // [64][32] float4, swizzled

  const int t    = threadIdx.x;
  const int row0 = blockIdx.x * 64;
  const int col0 = blockIdx.y * 64;

#pragma unroll
  for (int i = 0; i < 8; ++i) {
    const int fi = t + i * 256;
    const int k  = fi >> 4;
    const int j4 = (fi & 15) << 2;
    *(float4*)&Wl[k * 64 + j4] = *(const float4*)&W[(size_t)k * NOUT + col0 + j4];
  }
#pragma unroll
  for (int i = 0; i < 8; ++i) {
    const int fi = t + i * 256;
    const int rr = fi >> 5;
    const int q  = fi & 31;
    if (row0 + rr < M)
      X4[rr * 32 + (q ^ ((rr >> 2) & 7))] =
          *(const float4*)&X[(size_t)(row0 + rr) * 128 + q * 4];
  }
  __syncthreads();

  const int c   = (t & 15) << 2;
  const int rg  = (t >> 4) << 2;
  const int xsw = (t >> 4) & 7;

  float4 a0 = {0, 0, 0, 0}, a1 = a0, a2 = a0, a3 = a0;

#pragma unroll 4
  for (int k0 = 0; k0 < 128; k0 += 4) {
    const float4 w0 = *(const float4*)&Wl[(k0 + 0) * 64 + c];
    const float4 w1 = *(const float4*)&Wl[(k0 + 1) * 64 + c];
    const float4 w2 = *(const float4*)&Wl[(k0 + 2) * 64 + c];
    const float4 w3 = *(const float4*)&Wl[(k0 + 3) * 64 + c];
    const int q = (k0 >> 2) ^ xsw;
    const float4 x0 = X4[(rg + 0) * 32 + q];
    const float4 x1 = X4[(rg + 1) * 32 + q];
    const float4 x2 = X4[(rg + 2) * 32 + q];
    const float4 x3 = X4[(rg + 3) * 32 + q];
    fma4v(a0, w0, x0.x); fma4v(a0, w1, x0.y); fma4v(a0, w2, x0.z); fma4v(a0, w3, x0.w);
    fma4v(a1, w0, x1.x); fma4v(a1, w1, x1.y); fma4v(a1, w2, x1.z); fma4v(a1, w3, x1.w);
    fma4v(a2, w0, x2.x); fma4v(a2, w1, x2.y); fma4v(a2, w2, x2.z); fma4v(a2, w3, x2.w);
    fma4v(a3, w0, x3.x); fma4v(a3, w1, x3.y); fma4v(a3, w2, x3.z); fma4v(a3, w3, x3.w);
  }

  const int rowb = row0 + rg;
#pragma unroll
  for (int rr = 0; rr < 4; ++rr) {
    if (rowb + rr < M) {
      const float s = rs[rowb + rr];
      const float4& a = rr == 0 ? a0 : rr == 1 ? a1 : rr == 2 ? a2 : a3;
      float4 o;
      o.x = a.x * s; o.y = a.y * s; o.z = a.z * s; o.w = a.w * s;
      *(float4*)&H[(size_t)(rowb + rr) * NOUT + col0 + c] = o;
    }
  }
}

// ---------------------------------------------------------------- gather (CSR, no atomics)
// one wave per dst node: acc[d] += rs_in[d] * sum_{e in CSR[d]} H[src_e]
template <int F>
__global__ __launch_bounds__(256) void gather_k(const float* __restrict__ H,
                                                const int* __restrict__ row_ptr,
                                                const int* __restrict__ csr,
                                                const float* __restrict__ rsin,
                                                float* __restrict__ acc) {
  const int node = (blockIdx.x * 256 + threadIdx.x) >> 6;
  const int lane = threadIdx.x & 63;
  if (node >= NN) return;
  const int beg = row_ptr[node];
  const int end = row_ptr[node + 1];
  if (beg == end) return;
  if (F == 128) {
    float2 s = {0.f, 0.f};
    for (int e = beg; e < end; ++e) {
      const int src = csr[e];
      const float2 h = *(const float2*)&H[(size_t)src * 128 + lane * 2];
      s.x += h.x; s.y += h.y;
    }
    const float sc = rsin[node];
    float2* ap = (float2*)&acc[(size_t)node * 128 + lane * 2];
    float2 a = *ap;
    a.x += s.x * sc; a.y += s.y * sc;
    *ap = a;
  } else {
    float s = 0.f;
    for (int e = beg; e < end; ++e) {
      const int src = csr[e];
      s += H[(size_t)src * F + lane];
    }
    const float sc = rsin[node];
    acc[(size_t)node * F + lane] += s * sc;
  }
}

// ---------------------------------------------------------------- launch
extern "C" void kernel_launch(void* const* d_in, const int* in_sizes, int n_in,
                              void* d_out, int out_size, void* d_ws, size_t ws_size,
                              hipStream_t stream) {
  const float* x     = (const float*)d_in[0];
  const int*   edges = (const int*)d_in[1];
  const float* W1    = (const float*)d_in[2];
  const float* b1    = (const float*)d_in[3];
  const float* W2    = (const float*)d_in[4];
  const float* b2    = (const float*)d_in[5];
  float* out = (float*)d_out;

  // workspace layout (floats/ints, 4B units)
  float* hbuf   = (float*)d_ws;                               // NN*128
  float* acc1   = hbuf + (size_t)NN * FHID;                   // NN*128
  float* rs_out = acc1 + (size_t)NN * FHID;                   // NR*NN
  float* rs_in  = rs_out + (size_t)NR * NN;                   // NR*NN
  int* cnt_out  = (int*)(rs_in + (size_t)NR * NN);            // NR*NN
  int* cnt_in   = cnt_out + (size_t)NR * NN;                  // NR*NN
  int* row_ptr  = cnt_in + (size_t)NR * NN;                   // NR*(NN+1)
  int* cursor   = row_ptr + (size_t)NR * (NN + 1);            // NR*NN
  int* bsum     = cursor + (size_t)NR * NN;                   // NR*128
  int* csr      = bsum + NR * 128;                            // NR*NE

  const int nb = (NN + SCAN_B - 1) / SCAN_B;  // 98

  // ---- degrees + CSR build (shared by both layers)
  hipMemsetAsync(cnt_out, 0, (size_t)2 * NR * NN * sizeof(int), stream);
  count_k<<<dim3((NE + 255) / 256, NR), 256, 0, stream>>>(edges, cnt_out, cnt_in);
  rs_k<<<(2 * NR * NN + 255) / 256, 256, 0, stream>>>(cnt_out, rs_out, 2 * NR * NN);
  scan1_k<<<dim3(nb, NR), 256, 0, stream>>>(cnt_in, cursor /*temp excl*/, bsum, NN);
  scan2_k<<<NR, 128, 0, stream>>>(bsum, nb);
  scan3_k<<<dim3((NN + 255) / 256, NR), 256, 0, stream>>>(cursor, bsum, row_ptr, cursor, NN);
  fill_k<<<dim3((NE + 255) / 256, NR), 256, 0, stream>>>(edges, cursor, csr);

  // ---- layer 1
  init_bias_k<FHID><<<((NN * FHID / 4) + 255) / 256, 256, 0, stream>>>(
      (float4*)acc1, (const float4*)b1, NN * FHID / 4);
  for (int r = 0; r < NR; ++r) {
    gemm_rs_k<FHID><<<dim3((NN + 63) / 64, FHID / 64), 256, 65536, stream>>>(
        x, W1 + (size_t)r * FIN * FHID, rs_out + (size_t)r * NN, hbuf, NN);
    gather_k<FHID><<<(NN * 64 + 255) / 256, 256, 0, stream>>>(
        hbuf, row_ptr + (size_t)r * (NN + 1), csr + (size_t)r * NE,
        rs_in + (size_t)r * NN, acc1);
  }
  relu4_k<<<((NN * FHID / 4) + 255) / 256, 256, 0, stream>>>((float4*)acc1, NN * FHID / 4);

  // ---- layer 2
  init_bias_k<FOUT><<<((NN * FOUT / 4) + 255) / 256, 256, 0, stream>>>(
      (float4*)out, (const float4*)b2, NN * FOUT / 4);
  for (int r = 0; r < NR; ++r) {
    gemm_rs_k<FOUT><<<dim3((NN + 63) / 64, FOUT / 64), 256, 65536, stream>>>(
        acc1, W2 + (size_t)r * FHID * FOUT, rs_out + (size_t)r * NN, hbuf, NN);
    gather_k<FOUT><<<(NN * 64 + 255) / 256, 256, 0, stream>>>(
        hbuf, row_ptr + (size_t)r * (NN + 1), csr + (size_t)r * NE,
        rs_in + (size_t)r * NN, out);
  }
}

// Round 3
// 438.351 us; speedup vs baseline: 4.8778x; 1.7468x over previous
//
#include <hip/hip_runtime.h>
#include <cstddef>
#include <cstdint>

#define NN   100000   // nodes
#define NR   4        // relations
#define NE   160000   // edges per relation
#define FIN  128
#define FHID 128
#define FOUT 64
#define SCAN_B 1024

typedef short bf16x8 __attribute__((ext_vector_type(8)));
typedef float f32x4  __attribute__((ext_vector_type(4)));

__device__ __forceinline__ unsigned short f2bf(float f) {  // RNE f32->bf16
  union { float f; unsigned u; } v; v.f = f;
  unsigned r = v.u + 0x7fffu + ((v.u >> 16) & 1u);
  return (unsigned short)(r >> 16);
}
__device__ __forceinline__ float bf2f(unsigned short h) {
  union { unsigned u; float f; } v; v.u = ((unsigned)h) << 16;
  return v.f;
}

// ---------------------------------------------------------------- degree counts
__global__ __launch_bounds__(256) void count_k(const int* __restrict__ edges,
                                               int* __restrict__ cnt_out,
                                               int* __restrict__ cnt_in) {
  const int r = blockIdx.y;
  const int e = blockIdx.x * 256 + threadIdx.x;
  if (e >= NE) return;
  const int s = edges[(size_t)r * 2 * NE + e];
  const int d = edges[(size_t)r * 2 * NE + NE + e];
  atomicAdd(&cnt_out[(size_t)r * NN + s], 1);
  atomicAdd(&cnt_in[(size_t)r * NN + d], 1);
}

__global__ __launch_bounds__(256) void rs_k(const int* __restrict__ cnt,
                                            float* __restrict__ rs, int n) {
  const int i = blockIdx.x * 256 + threadIdx.x;
  if (i < n) rs[i] = rsqrtf(fmaxf((float)cnt[i], 1.0f));
}

// ---------------------------------------------------------------- prefix scan (CSR row_ptr)
__global__ __launch_bounds__(256) void scan1_k(const int* __restrict__ cnt,
                                               int* __restrict__ excl,
                                               int* __restrict__ bsum, int n) {
  const int r = blockIdx.y, b = blockIdx.x, t = threadIdx.x;
  const int base = b * SCAN_B;
  int v[4]; int tl = 0;
#pragma unroll
  for (int i = 0; i < 4; ++i) {
    const int idx = base + t * 4 + i;
    v[i] = (idx < n) ? cnt[(size_t)r * n + idx] : 0;
    tl += v[i];
  }
  __shared__ int sm[256];
  sm[t] = tl;
  __syncthreads();
  for (int off = 1; off < 256; off <<= 1) {
    const int x = (t >= off) ? sm[t - off] : 0;
    __syncthreads();
    sm[t] += x;
    __syncthreads();
  }
  const int incl = sm[t];
  int run = incl - tl;
#pragma unroll
  for (int i = 0; i < 4; ++i) {
    const int idx = base + t * 4 + i;
    if (idx < n) excl[(size_t)r * n + idx] = run;
    run += v[i];
  }
  if (t == 255) bsum[r * 128 + b] = incl;
}

__global__ __launch_bounds__(128) void scan2_k(int* __restrict__ bsum, int nb) {
  const int r = blockIdx.x, t = threadIdx.x;
  __shared__ int sm[128];
  const int v = (t < nb) ? bsum[r * 128 + t] : 0;
  sm[t] = v;
  __syncthreads();
  for (int off = 1; off < 128; off <<= 1) {
    const int x = (t >= off) ? sm[t - off] : 0;
    __syncthreads();
    sm[t] += x;
    __syncthreads();
  }
  if (t < nb) bsum[r * 128 + t] = sm[t] - v;
}

__global__ __launch_bounds__(256) void scan3_k(const int* __restrict__ excl,
                                               const int* __restrict__ bsum,
                                               int* __restrict__ row_ptr,
                                               int* __restrict__ cursor, int n) {
  const int r = blockIdx.y;
  const int i = blockIdx.x * 256 + threadIdx.x;
  if (i < n) {
    const int v = excl[(size_t)r * n + i] + bsum[r * 128 + i / SCAN_B];
    row_ptr[(size_t)r * (n + 1) + i] = v;
    cursor[(size_t)r * n + i] = v;
  }
  if (i == 0) row_ptr[(size_t)r * (n + 1) + n] = NE;
}

__global__ __launch_bounds__(256) void fill_k(const int* __restrict__ edges,
                                              int* __restrict__ cursor,
                                              int* __restrict__ csr) {
  const int r = blockIdx.y;
  const int e = blockIdx.x * 256 + threadIdx.x;
  if (e >= NE) return;
  const int s = edges[(size_t)r * 2 * NE + e];
  const int d = edges[(size_t)r * 2 * NE + NE + e];
  const int pos = atomicAdd(&cursor[(size_t)r * NN + d], 1);
  csr[(size_t)r * NE + pos] = s;
}

// ---------------------------------------------------------------- converts
// x f32 -> bf16 (8 elems/thread)
__global__ __launch_bounds__(256) void cvtx_k(const float* __restrict__ x,
                                              unsigned short* __restrict__ xb, int n8) {
  const int i = blockIdx.x * 256 + threadIdx.x;
  if (i >= n8) return;
  const float4 a = *(const float4*)&x[i * 8];
  const float4 b = *(const float4*)&x[i * 8 + 4];
  unsigned short o[8];
  o[0] = f2bf(a.x); o[1] = f2bf(a.y); o[2] = f2bf(a.z); o[3] = f2bf(a.w);
  o[4] = f2bf(b.x); o[5] = f2bf(b.y); o[6] = f2bf(b.z); o[7] = f2bf(b.w);
  *(bf16x8*)&xb[i * 8] = *(bf16x8*)o;
}

// W [r][k=128][N] f32 -> Wt [r][N][k=128] bf16 (transpose + convert)
__global__ __launch_bounds__(256) void cvtw_k(const float* __restrict__ W,
                                              unsigned short* __restrict__ Wt,
                                              int N, int total) {
  const int i = blockIdx.x * 256 + threadIdx.x;
  if (i >= total) return;
  const int r = i / (128 * N);
  const int k = (i / N) % 128;
  const int n = i % N;
  Wt[((size_t)r * N + n) * 128 + k] = f2bf(W[i]);
}

// ---------------------------------------------------------------- MFMA GEMM
// H_r[row][col] = bf16( rs_r[row] * sum_k Xb[row][k] * W_r[k][col] ),  K=128, all r via blockIdx.z
// LDS: Xl [128 rows][16 slots of 8 bf16], XOR-swizzled slot ^= row&7 ; Wl same with n rows.
template <int NOUT>
__global__ __launch_bounds__(256) void gemm_mfma_k(const unsigned short* __restrict__ Xb,
                                                   const unsigned short* __restrict__ Wt,
                                                   const float* __restrict__ rs,
                                                   unsigned short* __restrict__ H, int M) {
  extern __shared__ unsigned short smem[];
  unsigned short* Xl = smem;             // 128*128
  unsigned short* Wl = smem + 128 * 128; // NOUT*128

  const int z = blockIdx.z;
  const unsigned short* Wtr = Wt + (size_t)z * NOUT * 128;
  const float* rsr = rs + (size_t)z * NN;
  unsigned short* Hr = H + (size_t)z * NN * NOUT;

  const int t = threadIdx.x;
  const int row0 = blockIdx.x * 128;

  // stage X tile: 128 rows x 16 slots(16B)
#pragma unroll
  for (int i = 0; i < 8; ++i) {
    const int fi = t + i * 256;
    const int r = fi >> 4;
    const int q = fi & 15;
    int gr = row0 + r;
    if (gr >= M) gr = M - 1;  // clamp; OOB rows never stored
    const bf16x8 v = *(const bf16x8*)&Xb[(size_t)gr * 128 + q * 8];
    *(bf16x8*)&Xl[r * 128 + ((q ^ (r & 7)) << 3)] = v;
  }
  // stage W tile: NOUT rows(n) x 16 slots
#pragma unroll
  for (int i = 0; i < NOUT * 16 / 256; ++i) {
    const int fi = t + i * 256;
    const int n = fi >> 4;
    const int q = fi & 15;
    const bf16x8 v = *(const bf16x8*)&Wtr[(size_t)n * 128 + q * 8];
    *(bf16x8*)&Wl[n * 128 + ((q ^ (n & 7)) << 3)] = v;
  }
  __syncthreads();

  const int wid = t >> 6;
  const int lane = t & 63;
  const int lg = lane >> 4;   // k-group
  const int lr = lane & 15;   // row (A) / col (B) within fragment
  const int key = lane & 7;   // swizzle key
  constexpr int NF = NOUT / 64;        // col frags per wave (2 or 1)
  const int nc0 = wid * (NOUT / 4);    // wave col base (32 or 16)

  f32x4 acc[8][NF];
#pragma unroll
  for (int mf = 0; mf < 8; ++mf)
#pragma unroll
    for (int nf = 0; nf < NF; ++nf) acc[mf][nf] = (f32x4){0.f, 0.f, 0.f, 0.f};

#pragma unroll
  for (int ks = 0; ks < 4; ++ks) {
    const int slot = (ks * 4 + lg) ^ key;
    bf16x8 b[NF];
#pragma unroll
    for (int nf = 0; nf < NF; ++nf) {
      const int n = nc0 + nf * 16 + lr;
      b[nf] = *(const bf16x8*)&Wl[n * 128 + slot * 8];
    }
#pragma unroll
    for (int mf = 0; mf < 8; ++mf) {
      const int r = mf * 16 + lr;
      const bf16x8 a = *(const bf16x8*)&Xl[r * 128 + slot * 8];
#pragma unroll
      for (int nf = 0; nf < NF; ++nf)
        acc[mf][nf] = __builtin_amdgcn_mfma_f32_16x16x32_bf16(a, b[nf], acc[mf][nf], 0, 0, 0);
    }
  }

  // epilogue: D[row=(lg*4+i)][col=lr] per 16x16 frag; scale by rs[row], cvt bf16
#pragma unroll
  for (int mf = 0; mf < 8; ++mf) {
#pragma unroll
    for (int i = 0; i < 4; ++i) {
      const int row = row0 + mf * 16 + lg * 4 + i;
      if (row < M) {
        const float s = rsr[row];
#pragma unroll
        for (int nf = 0; nf < NF; ++nf) {
          const int col = nc0 + nf * 16 + lr;
          Hr[(size_t)row * NOUT + col] = f2bf(acc[mf][nf][i] * s);
        }
      }
    }
  }
}

// ---------------------------------------------------------------- fused gathers
// layer 1: h1b[node] = bf16( relu( sum_r rs_in_r[node] * sum_{e in csr_r[node]} H_r[src_e] + sum_r b1_r ) )
__global__ __launch_bounds__(256) void gather1_k(const unsigned short* __restrict__ H,
                                                 const int* __restrict__ row_ptr,
                                                 const int* __restrict__ csr,
                                                 const float* __restrict__ rsin,
                                                 const float* __restrict__ b1,
                                                 unsigned short* __restrict__ h1b) {
  const int node = blockIdx.x * 4 + (threadIdx.x >> 6);
  const int lane = threadIdx.x & 63;
  if (node >= NN) return;
  const int f = lane * 2;

  float2 s;
  {
    const float2 c0 = *(const float2*)&b1[0 * 128 + f];
    const float2 c1 = *(const float2*)&b1[1 * 128 + f];
    const float2 c2 = *(const float2*)&b1[2 * 128 + f];
    const float2 c3 = *(const float2*)&b1[3 * 128 + f];
    s.x = c0.x + c1.x + c2.x + c3.x;
    s.y = c0.y + c1.y + c2.y + c3.y;
  }
#pragma unroll
  for (int r = 0; r < NR; ++r) {
    const int beg = row_ptr[(size_t)r * (NN + 1) + node];
    const int end = row_ptr[(size_t)r * (NN + 1) + node + 1];
    if (beg == end) continue;
    const float sc = rsin[(size_t)r * NN + node];
    float2 acc = {0.f, 0.f};
    for (int e = beg; e < end; ++e) {
      const int src = csr[(size_t)r * NE + e];
      const unsigned u = *(const unsigned*)&H[((size_t)r * NN + src) * 128 + f];
      acc.x += bf2f((unsigned short)(u & 0xffff));
      acc.y += bf2f((unsigned short)(u >> 16));
    }
    s.x = fmaf(acc.x, sc, s.x);
    s.y = fmaf(acc.y, sc, s.y);
  }
  s.x = fmaxf(s.x, 0.f);
  s.y = fmaxf(s.y, 0.f);
  const unsigned o = (unsigned)f2bf(s.x) | ((unsigned)f2bf(s.y) << 16);
  *(unsigned*)&h1b[(size_t)node * 128 + f] = o;
}

// layer 2: out[node] = sum_r rs_in_r[node] * gather_r(H2_r) + sum_r b2_r   (f32, F=64)
__global__ __launch_bounds__(256) void gather2_k(const unsigned short* __restrict__ H,
                                                 const int* __restrict__ row_ptr,
                                                 const int* __restrict__ csr,
                                                 const float* __restrict__ rsin,
                                                 const float* __restrict__ b2,
                                                 float* __restrict__ out) {
  const int node = blockIdx.x * 4 + (threadIdx.x >> 6);
  const int lane = threadIdx.x & 63;
  if (node >= NN) return;

  float s = b2[0 * 64 + lane] + b2[1 * 64 + lane] + b2[2 * 64 + lane] + b2[3 * 64 + lane];
#pragma unroll
  for (int r = 0; r < NR; ++r) {
    const int beg = row_ptr[(size_t)r * (NN + 1) + node];
    const int end = row_ptr[(size_t)r * (NN + 1) + node + 1];
    if (beg == end) continue;
    const float sc = rsin[(size_t)r * NN + node];
    float acc = 0.f;
    for (int e = beg; e < end; ++e) {
      const int src = csr[(size_t)r * NE + e];
      acc += bf2f(H[((size_t)r * NN + src) * 64 + lane]);
    }
    s = fmaf(acc, sc, s);
  }
  out[(size_t)node * 64 + lane] = s;
}

// ---------------------------------------------------------------- launch
extern "C" void kernel_launch(void* const* d_in, const int* in_sizes, int n_in,
                              void* d_out, int out_size, void* d_ws, size_t ws_size,
                              hipStream_t stream) {
  const float* x     = (const float*)d_in[0];
  const int*   edges = (const int*)d_in[1];
  const float* W1    = (const float*)d_in[2];
  const float* b1    = (const float*)d_in[3];
  const float* W2    = (const float*)d_in[4];
  const float* b2    = (const float*)d_in[5];
  float* out = (float*)d_out;

  // ---- workspace layout (2B units for bf16 buffers)
  unsigned short* xb   = (unsigned short*)d_ws;              // NN*128 bf16 (aliased by h1b later)
  unsigned short* h1b  = xb;                                 // reuse: written after xb's last read
  unsigned short* Hbuf = xb + (size_t)NN * 128;              // NR*NN*128 bf16 (layer2 reuses prefix)
  unsigned short* Wt1  = Hbuf + (size_t)NR * NN * 128;       // NR*128*128 bf16
  unsigned short* Wt2  = Wt1 + (size_t)NR * 128 * 128;       // NR*64*128 bf16
  float* rs_out = (float*)(Wt2 + (size_t)NR * 64 * 128);     // NR*NN
  float* rs_in  = rs_out + (size_t)NR * NN;                  // NR*NN
  int* cnt_out  = (int*)(rs_in + (size_t)NR * NN);           // NR*NN
  int* cnt_in   = cnt_out + (size_t)NR * NN;                 // NR*NN
  int* row_ptr  = cnt_in + (size_t)NR * NN;                  // NR*(NN+1)
  int* cursor   = row_ptr + (size_t)NR * (NN + 1);           // NR*NN
  int* bsum     = cursor + (size_t)NR * NN;                  // NR*128
  int* csr      = bsum + NR * 128;                           // NR*NE

  const int nb = (NN + SCAN_B - 1) / SCAN_B;

  // ---- CSR + degree prep (shared by both layers)
  hipMemsetAsync(cnt_out, 0, (size_t)2 * NR * NN * sizeof(int), stream);
  count_k<<<dim3((NE + 255) / 256, NR), 256, 0, stream>>>(edges, cnt_out, cnt_in);
  rs_k<<<(2 * NR * NN + 255) / 256, 256, 0, stream>>>(cnt_out, rs_out, 2 * NR * NN);
  scan1_k<<<dim3(nb, NR), 256, 0, stream>>>(cnt_in, cursor, bsum, NN);
  scan2_k<<<NR, 128, 0, stream>>>(bsum, nb);
  scan3_k<<<dim3((NN + 255) / 256, NR), 256, 0, stream>>>(cursor, bsum, row_ptr, cursor, NN);
  fill_k<<<dim3((NE + 255) / 256, NR), 256, 0, stream>>>(edges, cursor, csr);

  // ---- bf16 conversions
  cvtx_k<<<((NN * 128 / 8) + 255) / 256, 256, 0, stream>>>(x, xb, NN * 128 / 8);
  cvtw_k<<<(NR * 128 * 128 + 255) / 256, 256, 0, stream>>>(W1, Wt1, 128, NR * 128 * 128);
  cvtw_k<<<(NR * 128 * 64 + 255) / 256, 256, 0, stream>>>(W2, Wt2, 64, NR * 128 * 64);

  const int mblocks = (NN + 127) / 128;

  // ---- layer 1: GEMM (all 4 relations) then fused gather+bias+relu -> h1b
  gemm_mfma_k<128><<<dim3(mblocks, 1, NR), 256, (128 * 128 + 128 * 128) * 2, stream>>>(
      xb, Wt1, rs_out, Hbuf, NN);
  gather1_k<<<(NN + 3) / 4, 256, 0, stream>>>(Hbuf, row_ptr, csr, rs_in, b1, h1b);

  // ---- layer 2: GEMM (all 4 relations) then fused gather+bias -> out
  gemm_mfma_k<64><<<dim3(mblocks, 1, NR), 256, (128 * 128 + 64 * 128) * 2, stream>>>(
      h1b, Wt2, rs_out, Hbuf, NN);
  gather2_k<<<(NN + 3) / 4, 256, 0, stream>>>(Hbuf, row_ptr, csr, rs_in, b2, out);
}

// Round 4
// 339.277 us; speedup vs baseline: 6.3023x; 1.2920x over previous
//
#include <hip/hip_runtime.h>
#include <cstddef>
#include <cstdint>

#define NN   100000   // nodes
#define NR   4        // relations
#define NE   160000   // edges per relation
#define SCAN_B 1024

typedef short bf16x8 __attribute__((ext_vector_type(8)));
typedef float f32x4  __attribute__((ext_vector_type(4)));

__device__ __forceinline__ unsigned short f2bf(float f) {  // RNE f32->bf16
  union { float f; unsigned u; } v; v.f = f;
  unsigned r = v.u + 0x7fffu + ((v.u >> 16) & 1u);
  return (unsigned short)(r >> 16);
}
__device__ __forceinline__ float bf2f(unsigned short h) {
  union { unsigned u; float f; } v; v.u = ((unsigned)h) << 16;
  return v.f;
}

// async global->LDS, 16B per lane, linear LDS dest (base + lane*16)
__device__ __forceinline__ void gll16(const unsigned short* g, unsigned short* l) {
  __builtin_amdgcn_global_load_lds(
      (const __attribute__((address_space(1))) void*)g,
      (__attribute__((address_space(3))) void*)l, 16, 0, 0);
}

// ---------------------------------------------------------------- degree counts
__global__ __launch_bounds__(256) void count_k(const int* __restrict__ edges,
                                               int* __restrict__ cnt_out,
                                               int* __restrict__ cnt_in) {
  const int r = blockIdx.y;
  const int e = blockIdx.x * 256 + threadIdx.x;
  if (e >= NE) return;
  const int s = edges[(size_t)r * 2 * NE + e];
  const int d = edges[(size_t)r * 2 * NE + NE + e];
  atomicAdd(&cnt_out[(size_t)r * NN + s], 1);
  atomicAdd(&cnt_in[(size_t)r * NN + d], 1);
}

__global__ __launch_bounds__(256) void rs_k(const int* __restrict__ cnt,
                                            float* __restrict__ rs, int n) {
  const int i = blockIdx.x * 256 + threadIdx.x;
  if (i < n) rs[i] = rsqrtf(fmaxf((float)cnt[i], 1.0f));
}

// ---------------------------------------------------------------- combined-CSR scan
// scan1: per-block exclusive scan of sum_r cnt_in[r][i] -> excl, block totals -> bsum
__global__ __launch_bounds__(256) void scan1_k(const int* __restrict__ cnt_in,
                                               int* __restrict__ excl,
                                               int* __restrict__ bsum) {
  const int b = blockIdx.x, t = threadIdx.x;
  const int base = b * SCAN_B;
  int v[4]; int tl = 0;
#pragma unroll
  for (int i = 0; i < 4; ++i) {
    const int idx = base + t * 4 + i;
    int c = 0;
    if (idx < NN) {
      c = cnt_in[idx] + cnt_in[NN + idx] + cnt_in[2 * NN + idx] + cnt_in[3 * NN + idx];
    }
    v[i] = c;
    tl += c;
  }
  __shared__ int sm[256];
  sm[t] = tl;
  __syncthreads();
  for (int off = 1; off < 256; off <<= 1) {
    const int x = (t >= off) ? sm[t - off] : 0;
    __syncthreads();
    sm[t] += x;
    __syncthreads();
  }
  const int incl = sm[t];
  int run = incl - tl;
#pragma unroll
  for (int i = 0; i < 4; ++i) {
    const int idx = base + t * 4 + i;
    if (idx < NN) excl[idx] = run;
    run += v[i];
  }
  if (t == 255) bsum[b] = incl;
}

__global__ __launch_bounds__(128) void scan2_k(int* __restrict__ bsum, int nb) {
  const int t = threadIdx.x;
  __shared__ int sm[128];
  const int v = (t < nb) ? bsum[t] : 0;
  sm[t] = v;
  __syncthreads();
  for (int off = 1; off < 128; off <<= 1) {
    const int x = (t >= off) ? sm[t - off] : 0;
    __syncthreads();
    sm[t] += x;
    __syncthreads();
  }
  if (t < nb) bsum[t] = sm[t] - v;
}

__global__ __launch_bounds__(256) void scan3_k(const int* __restrict__ excl,
                                               const int* __restrict__ bsum,
                                               int* __restrict__ row_ptr,
                                               int* __restrict__ cursor) {
  const int i = blockIdx.x * 256 + threadIdx.x;
  if (i < NN) {
    const int v = excl[i] + bsum[i / SCAN_B];
    row_ptr[i] = v;
    cursor[i] = v;
  }
  if (i == 0) row_ptr[NN] = NR * NE;
}

// fill combined CSR: payload = (r*NN+src, bits(rs_in[r][dst]))
__global__ __launch_bounds__(256) void fill_k(const int* __restrict__ edges,
                                              const float* __restrict__ rs_in,
                                              int* __restrict__ cursor,
                                              int2* __restrict__ csr) {
  const int r = blockIdx.y;
  const int e = blockIdx.x * 256 + threadIdx.x;
  if (e >= NE) return;
  const int s = edges[(size_t)r * 2 * NE + e];
  const int d = edges[(size_t)r * 2 * NE + NE + e];
  const int pos = atomicAdd(&cursor[d], 1);
  csr[pos] = make_int2(r * NN + s, __float_as_int(rs_in[(size_t)r * NN + d]));
}

// ---------------------------------------------------------------- converts
__global__ __launch_bounds__(256) void cvtx_k(const float* __restrict__ x,
                                              unsigned short* __restrict__ xb, int n8) {
  const int i = blockIdx.x * 256 + threadIdx.x;
  if (i >= n8) return;
  const float4 a = *(const float4*)&x[i * 8];
  const float4 b = *(const float4*)&x[i * 8 + 4];
  unsigned short o[8];
  o[0] = f2bf(a.x); o[1] = f2bf(a.y); o[2] = f2bf(a.z); o[3] = f2bf(a.w);
  o[4] = f2bf(b.x); o[5] = f2bf(b.y); o[6] = f2bf(b.z); o[7] = f2bf(b.w);
  *(bf16x8*)&xb[i * 8] = *(bf16x8*)o;
}

// W [r][k=128][N] f32 -> Wt [r][N][k=128] bf16
__global__ __launch_bounds__(256) void cvtw_k(const float* __restrict__ W,
                                              unsigned short* __restrict__ Wt,
                                              int N, int total) {
  const int i = blockIdx.x * 256 + threadIdx.x;
  if (i >= total) return;
  const int r = i / (128 * N);
  const int k = (i / N) % 128;
  const int n = i % N;
  Wt[((size_t)r * N + n) * 128 + k] = f2bf(W[i]);
}

// ---------------------------------------------------------------- MFMA GEMM v2
// H_r[row][col] = bf16( rs_r[row] * sum_k Xb[row][k] * Wt_r[col][k] ), K=128.
// Block: 256 thr, loops row tiles of 128 with double-buffered X LDS (2x32KB).
// W fragments live in registers (loaded once). Waves: 64x64 (NOUT=128: 2x2 grid)
// or 32x64 (NOUT=64: 4x1 grid). X tile XOR-swizzled: 16B slot s at row r holds
// logical chunk s^(r&7); staged via global_load_lds with pre-swizzled source.
template <int NOUT>
__global__ __launch_bounds__(256, 2) void gemm2_k(const unsigned short* __restrict__ Xb,
                                                  const unsigned short* __restrict__ Wt,
                                                  const float* __restrict__ rs,
                                                  unsigned short* __restrict__ H,
                                                  int M, int ntiles) {
  __shared__ unsigned short Xl[2][128 * 128];  // 2 x 32KB

  const int z = blockIdx.z;
  const unsigned short* Wtr = Wt + (size_t)z * NOUT * 128;
  const float* rsr = rs + (size_t)z * NN;
  unsigned short* Hr = H + (size_t)z * NN * NOUT;

  const int t = threadIdx.x;
  const int wid = t >> 6;
  const int lane = t & 63;
  const int lg = lane >> 4;   // k-group
  const int lr = lane & 15;   // row (A) / col (B) within fragment

  constexpr int MF = (NOUT == 128) ? 4 : 2;   // row frags per wave
  constexpr int NF = 4;                        // col frags per wave (64 cols)
  const int rowg = (NOUT == 128) ? (wid & 1) : wid;
  const int colg = (NOUT == 128) ? (wid >> 1) : 0;
  const int rbase = rowg * MF * 16;
  const int cbase = colg * 64;

  // preload W fragments (once per block; L2-hot)
  bf16x8 bw[NF][4];
#pragma unroll
  for (int nf = 0; nf < NF; ++nf)
#pragma unroll
    for (int ks = 0; ks < 4; ++ks)
      bw[nf][ks] = *(const bf16x8*)&Wtr[(size_t)(cbase + nf * 16 + lr) * 128 + ks * 32 + lg * 8];

  // staging: wave stages rows wid*32..wid*32+31 (8KB), 8 x 16B per thread.
  // LDS dest linear; global source pre-swizzled (chunk q = s ^ (r&7)).
  auto stage = [&](int buf, int tile) {
    const int row0 = tile * 128;
#pragma unroll
    for (int i = 0; i < 8; ++i) {
      const int rl = wid * 32 + i * 4 + (lane >> 4);
      int gr = row0 + rl;
      if (gr >= M) gr = M - 1;  // clamp; masked at store
      const int q = (lane & 15) ^ (rl & 7);
      gll16(&Xb[(size_t)gr * 128 + q * 8], &Xl[buf][rl * 128 + (lane & 15) * 8]);
    }
  };

  int tile = blockIdx.x;
  if (tile >= ntiles) return;
  stage(0, tile);
  __syncthreads();
  int buf = 0;

  for (; tile < ntiles; tile += gridDim.x) {
    const int nxt = tile + gridDim.x;
    if (nxt < ntiles) stage(buf ^ 1, nxt);

    f32x4 acc[MF][NF];
#pragma unroll
    for (int mf = 0; mf < MF; ++mf)
#pragma unroll
      for (int nf = 0; nf < NF; ++nf) acc[mf][nf] = (f32x4){0.f, 0.f, 0.f, 0.f};

#pragma unroll
    for (int ks = 0; ks < 4; ++ks) {
#pragma unroll
      for (int mf = 0; mf < MF; ++mf) {
        const int r = rbase + mf * 16 + lr;
        const bf16x8 a =
            *(const bf16x8*)&Xl[buf][r * 128 + (((ks * 4 + lg) ^ (lr & 7)) << 3)];
#pragma unroll
        for (int nf = 0; nf < NF; ++nf)
          acc[mf][nf] = __builtin_amdgcn_mfma_f32_16x16x32_bf16(a, bw[nf][ks], acc[mf][nf], 0, 0, 0);
      }
    }

    // epilogue: D row = lg*4+i, col = lr (per frag); scale by rs, cvt bf16
    const int row0 = tile * 128;
#pragma unroll
    for (int mf = 0; mf < MF; ++mf) {
#pragma unroll
      for (int i = 0; i < 4; ++i) {
        const int row = row0 + rbase + mf * 16 + lg * 4 + i;
        if (row < M) {
          const float s = rsr[row];
#pragma unroll
          for (int nf = 0; nf < NF; ++nf)
            Hr[(size_t)row * NOUT + cbase + nf * 16 + lr] = f2bf(acc[mf][nf][i] * s);
        }
      }
    }
    __syncthreads();  // drains staged loads for next tile; releases buf
    buf ^= 1;
  }
}

// ---------------------------------------------------------------- fused gathers (combined CSR)
// layer 1: h1b[d] = bf16(relu( sum_e w_e * H[srcrow_e] + sum_r b1_r ))
__global__ __launch_bounds__(256) void gather1_k(const unsigned short* __restrict__ H,
                                                 const int* __restrict__ row_ptr,
                                                 const int2* __restrict__ csr,
                                                 const float* __restrict__ b1,
                                                 unsigned short* __restrict__ h1b) {
  const int node = blockIdx.x * 4 + (threadIdx.x >> 6);
  const int lane = threadIdx.x & 63;
  if (node >= NN) return;
  const int f = lane * 2;

  float2 s;
  {
    const float2 c0 = *(const float2*)&b1[0 * 128 + f];
    const float2 c1 = *(const float2*)&b1[1 * 128 + f];
    const float2 c2 = *(const float2*)&b1[2 * 128 + f];
    const float2 c3 = *(const float2*)&b1[3 * 128 + f];
    s.x = c0.x + c1.x + c2.x + c3.x;
    s.y = c0.y + c1.y + c2.y + c3.y;
  }
  const int beg = row_ptr[node];
  const int end = row_ptr[node + 1];
  for (int e = beg; e < end; ++e) {
    const int2 p = csr[e];
    const float w = __int_as_float(p.y);
    const unsigned u = *(const unsigned*)&H[(size_t)p.x * 128 + f];
    s.x = fmaf(bf2f((unsigned short)(u & 0xffff)), w, s.x);
    s.y = fmaf(bf2f((unsigned short)(u >> 16)), w, s.y);
  }
  s.x = fmaxf(s.x, 0.f);
  s.y = fmaxf(s.y, 0.f);
  const unsigned o = (unsigned)f2bf(s.x) | ((unsigned)f2bf(s.y) << 16);
  *(unsigned*)&h1b[(size_t)node * 128 + f] = o;
}

// layer 2: out[d] = sum_e w_e * H2[srcrow_e] + sum_r b2_r   (f32, F=64)
__global__ __launch_bounds__(256) void gather2_k(const unsigned short* __restrict__ H,
                                                 const int* __restrict__ row_ptr,
                                                 const int2* __restrict__ csr,
                                                 const float* __restrict__ b2,
                                                 float* __restrict__ out) {
  const int node = blockIdx.x * 4 + (threadIdx.x >> 6);
  const int lane = threadIdx.x & 63;
  if (node >= NN) return;

  float s = b2[0 * 64 + lane] + b2[1 * 64 + lane] + b2[2 * 64 + lane] + b2[3 * 64 + lane];
  const int beg = row_ptr[node];
  const int end = row_ptr[node + 1];
  for (int e = beg; e < end; ++e) {
    const int2 p = csr[e];
    const float w = __int_as_float(p.y);
    s = fmaf(bf2f(H[(size_t)p.x * 64 + lane]), w, s);
  }
  out[(size_t)node * 64 + lane] = s;
}

// ---------------------------------------------------------------- launch
extern "C" void kernel_launch(void* const* d_in, const int* in_sizes, int n_in,
                              void* d_out, int out_size, void* d_ws, size_t ws_size,
                              hipStream_t stream) {
  const float* x     = (const float*)d_in[0];
  const int*   edges = (const int*)d_in[1];
  const float* W1    = (const float*)d_in[2];
  const float* b1    = (const float*)d_in[3];
  const float* W2    = (const float*)d_in[4];
  const float* b2    = (const float*)d_in[5];
  float* out = (float*)d_out;

  // ---- workspace layout
  unsigned short* xb   = (unsigned short*)d_ws;            // NN*128 bf16
  unsigned short* h1b  = xb;                               // reuse after layer1 GEMM
  unsigned short* Hbuf = xb + (size_t)NN * 128;            // NR*NN*128 bf16
  unsigned short* Wt1  = Hbuf + (size_t)NR * NN * 128;     // NR*128*128 bf16
  unsigned short* Wt2  = Wt1 + (size_t)NR * 128 * 128;     // NR*64*128 bf16
  float* rs_out = (float*)(Wt2 + (size_t)NR * 64 * 128);   // NR*NN
  float* rs_in  = rs_out + (size_t)NR * NN;                // NR*NN
  int* cnt_out  = (int*)(rs_in + (size_t)NR * NN);         // NR*NN
  int* cnt_in   = cnt_out + (size_t)NR * NN;               // NR*NN
  int* row_ptr  = cnt_in + (size_t)NR * NN;                // NN+1
  int* cursor   = row_ptr + (NN + 1);                      // NN
  int* bsum     = cursor + NN;                             // 128
  int2* csr     = (int2*)(bsum + 128);                     // NR*NE int2

  const int nb = (NN + SCAN_B - 1) / SCAN_B;  // 98

  // ---- degrees + combined CSR
  hipMemsetAsync(cnt_out, 0, (size_t)2 * NR * NN * sizeof(int), stream);
  count_k<<<dim3((NE + 255) / 256, NR), 256, 0, stream>>>(edges, cnt_out, cnt_in);
  rs_k<<<(2 * NR * NN + 255) / 256, 256, 0, stream>>>(cnt_out, rs_out, 2 * NR * NN);
  scan1_k<<<nb, 256, 0, stream>>>(cnt_in, cursor /*excl temp*/, bsum);
  scan2_k<<<1, 128, 0, stream>>>(bsum, nb);
  scan3_k<<<(NN + 255) / 256, 256, 0, stream>>>(cursor, bsum, row_ptr, cursor);
  fill_k<<<dim3((NE + 255) / 256, NR), 256, 0, stream>>>(edges, rs_in, cursor, csr);

  // ---- bf16 conversions
  cvtx_k<<<((NN * 128 / 8) + 255) / 256, 256, 0, stream>>>(x, xb, NN * 128 / 8);
  cvtw_k<<<(NR * 128 * 128 + 255) / 256, 256, 0, stream>>>(W1, Wt1, 128, NR * 128 * 128);
  cvtw_k<<<(NR * 128 * 64 + 255) / 256, 256, 0, stream>>>(W2, Wt2, 64, NR * 128 * 64);

  const int ntiles = (NN + 127) / 128;  // 782

  // ---- layer 1
  gemm2_k<128><<<dim3(128, 1, NR), 256, 0, stream>>>(xb, Wt1, rs_out, Hbuf, NN, ntiles);
  gather1_k<<<(NN + 3) / 4, 256, 0, stream>>>(Hbuf, row_ptr, csr, b1, h1b);

  // ---- layer 2
  gemm2_k<64><<<dim3(128, 1, NR), 256, 0, stream>>>(h1b, Wt2, rs_out, Hbuf, NN, ntiles);
  gather2_k<<<(NN + 3) / 4, 256, 0, stream>>>(Hbuf, row_ptr, csr, b2, out);
}

// Round 5
// 271.055 us; speedup vs baseline: 7.8885x; 1.2517x over previous
//
#include <hip/hip_runtime.h>
#include <cstddef>
#include <cstdint>

#define NN   100000   // nodes
#define NR   4        // relations
#define NE   160000   // edges per relation
#define SCAN_B 1024

typedef short bf16x8 __attribute__((ext_vector_type(8)));
typedef float f32x4  __attribute__((ext_vector_type(4)));

__device__ __forceinline__ unsigned short f2bf(float f) {  // RNE f32->bf16
  union { float f; unsigned u; } v; v.f = f;
  unsigned r = v.u + 0x7fffu + ((v.u >> 16) & 1u);
  return (unsigned short)(r >> 16);
}
__device__ __forceinline__ float bf2f(unsigned short h) {
  union { unsigned u; float f; } v; v.u = ((unsigned)h) << 16;
  return v.f;
}

// async global->LDS, 16B per lane, linear LDS dest
__device__ __forceinline__ void gll16(const unsigned short* g, unsigned short* l) {
  __builtin_amdgcn_global_load_lds(
      (const __attribute__((address_space(1))) void*)g,
      (__attribute__((address_space(3))) void*)l, 16, 0, 0);
}

// ---------------------------------------------------------------- degree counts
__global__ __launch_bounds__(256) void count_k(const int* __restrict__ edges,
                                               int* __restrict__ cnt_out,
                                               int* __restrict__ cnt_in) {
  const int r = blockIdx.y;
  const int e = blockIdx.x * 256 + threadIdx.x;
  if (e >= NE) return;
  const int s = edges[(size_t)r * 2 * NE + e];
  const int d = edges[(size_t)r * 2 * NE + NE + e];
  atomicAdd(&cnt_out[(size_t)r * NN + s], 1);
  atomicAdd(&cnt_in[(size_t)r * NN + d], 1);
}

__global__ __launch_bounds__(256) void rs_k(const int* __restrict__ cnt,
                                            float* __restrict__ rs, int n) {
  const int i = blockIdx.x * 256 + threadIdx.x;
  if (i < n) rs[i] = rsqrtf(fmaxf((float)cnt[i], 1.0f));
}

// ---------------------------------------------------------------- combined-CSR scan
__global__ __launch_bounds__(256) void scan1_k(const int* __restrict__ cnt_in,
                                               int* __restrict__ excl,
                                               int* __restrict__ bsum) {
  const int b = blockIdx.x, t = threadIdx.x;
  const int base = b * SCAN_B;
  int v[4]; int tl = 0;
#pragma unroll
  for (int i = 0; i < 4; ++i) {
    const int idx = base + t * 4 + i;
    int c = 0;
    if (idx < NN) {
      c = cnt_in[idx] + cnt_in[NN + idx] + cnt_in[2 * NN + idx] + cnt_in[3 * NN + idx];
    }
    v[i] = c;
    tl += c;
  }
  __shared__ int sm[256];
  sm[t] = tl;
  __syncthreads();
  for (int off = 1; off < 256; off <<= 1) {
    const int x = (t >= off) ? sm[t - off] : 0;
    __syncthreads();
    sm[t] += x;
    __syncthreads();
  }
  const int incl = sm[t];
  int run = incl - tl;
#pragma unroll
  for (int i = 0; i < 4; ++i) {
    const int idx = base + t * 4 + i;
    if (idx < NN) excl[idx] = run;
    run += v[i];
  }
  if (t == 255) bsum[b] = incl;
}

__global__ __launch_bounds__(128) void scan2_k(int* __restrict__ bsum, int nb) {
  const int t = threadIdx.x;
  __shared__ int sm[128];
  const int v = (t < nb) ? bsum[t] : 0;
  sm[t] = v;
  __syncthreads();
  for (int off = 1; off < 128; off <<= 1) {
    const int x = (t >= off) ? sm[t - off] : 0;
    __syncthreads();
    sm[t] += x;
    __syncthreads();
  }
  if (t < nb) bsum[t] = sm[t] - v;
}

__global__ __launch_bounds__(256) void scan3_k(const int* __restrict__ excl,
                                               const int* __restrict__ bsum,
                                               int* __restrict__ row_ptr,
                                               int* __restrict__ cursor) {
  const int i = blockIdx.x * 256 + threadIdx.x;
  if (i < NN) {
    const int v = excl[i] + bsum[i / SCAN_B];
    row_ptr[i] = v;
    cursor[i] = v;
  }
  if (i == 0) row_ptr[NN] = NR * NE;
}

// fill combined CSR: payload = (r*NN+src, bits(rs_in[r][dst]))
__global__ __launch_bounds__(256) void fill_k(const int* __restrict__ edges,
                                              const float* __restrict__ rs_in,
                                              int* __restrict__ cursor,
                                              int2* __restrict__ csr) {
  const int r = blockIdx.y;
  const int e = blockIdx.x * 256 + threadIdx.x;
  if (e >= NE) return;
  const int s = edges[(size_t)r * 2 * NE + e];
  const int d = edges[(size_t)r * 2 * NE + NE + e];
  const int pos = atomicAdd(&cursor[d], 1);
  csr[pos] = make_int2(r * NN + s, __float_as_int(rs_in[(size_t)r * NN + d]));
}

// summed biases: bs1[128] = sum_r b1[r][:], bs2[64] = sum_r b2[r][:]
__global__ __launch_bounds__(128) void bias_sum_k(const float* __restrict__ b1,
                                                  const float* __restrict__ b2,
                                                  float* __restrict__ bs1,
                                                  float* __restrict__ bs2) {
  const int t = threadIdx.x;
  bs1[t] = b1[t] + b1[128 + t] + b1[256 + t] + b1[384 + t];
  if (t < 64) bs2[t] = b2[t] + b2[64 + t] + b2[128 + t] + b2[192 + t];
}

// ---------------------------------------------------------------- converts
__global__ __launch_bounds__(256) void cvtx_k(const float* __restrict__ x,
                                              unsigned short* __restrict__ xb, int n8) {
  const int i = blockIdx.x * 256 + threadIdx.x;
  if (i >= n8) return;
  const float4 a = *(const float4*)&x[i * 8];
  const float4 b = *(const float4*)&x[i * 8 + 4];
  unsigned short o[8];
  o[0] = f2bf(a.x); o[1] = f2bf(a.y); o[2] = f2bf(a.z); o[3] = f2bf(a.w);
  o[4] = f2bf(b.x); o[5] = f2bf(b.y); o[6] = f2bf(b.z); o[7] = f2bf(b.w);
  *(bf16x8*)&xb[i * 8] = *(bf16x8*)o;
}

// W [r][k=128][N] f32 -> Wt [r][N][k=128] bf16
__global__ __launch_bounds__(256) void cvtw_k(const float* __restrict__ W,
                                              unsigned short* __restrict__ Wt,
                                              int N, int total) {
  const int i = blockIdx.x * 256 + threadIdx.x;
  if (i >= total) return;
  const int r = i / (128 * N);
  const int k = (i / N) % 128;
  const int n = i % N;
  Wt[((size_t)r * N + n) * 128 + k] = f2bf(W[i]);
}

// ---------------------------------------------------------------- MFMA GEMM v2 (unchanged from R4)
template <int NOUT>
__global__ __launch_bounds__(256, 2) void gemm2_k(const unsigned short* __restrict__ Xb,
                                                  const unsigned short* __restrict__ Wt,
                                                  const float* __restrict__ rs,
                                                  unsigned short* __restrict__ H,
                                                  int M, int ntiles) {
  __shared__ unsigned short Xl[2][128 * 128];  // 2 x 32KB

  const int z = blockIdx.z;
  const unsigned short* Wtr = Wt + (size_t)z * NOUT * 128;
  const float* rsr = rs + (size_t)z * NN;
  unsigned short* Hr = H + (size_t)z * NN * NOUT;

  const int t = threadIdx.x;
  const int wid = t >> 6;
  const int lane = t & 63;
  const int lg = lane >> 4;
  const int lr = lane & 15;

  constexpr int MF = (NOUT == 128) ? 4 : 2;
  constexpr int NF = 4;
  const int rowg = (NOUT == 128) ? (wid & 1) : wid;
  const int colg = (NOUT == 128) ? (wid >> 1) : 0;
  const int rbase = rowg * MF * 16;
  const int cbase = colg * 64;

  bf16x8 bw[NF][4];
#pragma unroll
  for (int nf = 0; nf < NF; ++nf)
#pragma unroll
    for (int ks = 0; ks < 4; ++ks)
      bw[nf][ks] = *(const bf16x8*)&Wtr[(size_t)(cbase + nf * 16 + lr) * 128 + ks * 32 + lg * 8];

  auto stage = [&](int buf, int tile) {
    const int row0 = tile * 128;
#pragma unroll
    for (int i = 0; i < 8; ++i) {
      const int rl = wid * 32 + i * 4 + (lane >> 4);
      int gr = row0 + rl;
      if (gr >= M) gr = M - 1;
      const int q = (lane & 15) ^ (rl & 7);
      gll16(&Xb[(size_t)gr * 128 + q * 8], &Xl[buf][rl * 128 + (lane & 15) * 8]);
    }
  };

  int tile = blockIdx.x;
  if (tile >= ntiles) return;
  stage(0, tile);
  __syncthreads();
  int buf = 0;

  for (; tile < ntiles; tile += gridDim.x) {
    const int nxt = tile + gridDim.x;
    if (nxt < ntiles) stage(buf ^ 1, nxt);

    f32x4 acc[MF][NF];
#pragma unroll
    for (int mf = 0; mf < MF; ++mf)
#pragma unroll
      for (int nf = 0; nf < NF; ++nf) acc[mf][nf] = (f32x4){0.f, 0.f, 0.f, 0.f};

#pragma unroll
    for (int ks = 0; ks < 4; ++ks) {
#pragma unroll
      for (int mf = 0; mf < MF; ++mf) {
        const int r = rbase + mf * 16 + lr;
        const bf16x8 a =
            *(const bf16x8*)&Xl[buf][r * 128 + (((ks * 4 + lg) ^ (lr & 7)) << 3)];
#pragma unroll
        for (int nf = 0; nf < NF; ++nf)
          acc[mf][nf] = __builtin_amdgcn_mfma_f32_16x16x32_bf16(a, bw[nf][ks], acc[mf][nf], 0, 0, 0);
      }
    }

    const int row0 = tile * 128;
#pragma unroll
    for (int mf = 0; mf < MF; ++mf) {
#pragma unroll
      for (int i = 0; i < 4; ++i) {
        const int row = row0 + rbase + mf * 16 + lg * 4 + i;
        if (row < M) {
          const float s = rsr[row];
#pragma unroll
          for (int nf = 0; nf < NF; ++nf)
            Hr[(size_t)row * NOUT + cbase + nf * 16 + lr] = f2bf(acc[mf][nf][i] * s);
        }
      }
    }
    __syncthreads();
    buf ^= 1;
  }
}

// ---------------------------------------------------------------- gathers, MLP version
// gather1: 1 node/wave; 4 edge-groups x 16 lanes; lane holds 8 features (16B).
__global__ __launch_bounds__(256) void gather1_k(const unsigned short* __restrict__ H,
                                                 const int* __restrict__ row_ptr,
                                                 const int2* __restrict__ csr,
                                                 const float* __restrict__ bs1,
                                                 unsigned short* __restrict__ h1b) {
  const int node = blockIdx.x * 4 + (threadIdx.x >> 6);
  const int lane = threadIdx.x & 63;
  if (node >= NN) return;
  const int g  = lane >> 4;   // edge slot 0..3
  const int fl = lane & 15;   // feature chunk (8 bf16)

  float acc[8];
#pragma unroll
  for (int j = 0; j < 8; ++j) acc[j] = 0.f;

  const int beg = row_ptr[node];
  const int end = row_ptr[node + 1];
  for (int e = beg + g; e < end; e += 4) {
    const int2 p = csr[e];
    const float w = __int_as_float(p.y);
    const bf16x8 h = *(const bf16x8*)&H[(size_t)p.x * 128 + fl * 8];
#pragma unroll
    for (int j = 0; j < 8; ++j)
      acc[j] = fmaf(bf2f((unsigned short)h[j]), w, acc[j]);
  }
  // combine the 4 edge-groups (same features, different edges)
#pragma unroll
  for (int j = 0; j < 8; ++j) {
    acc[j] += __shfl_xor(acc[j], 16);
    acc[j] += __shfl_xor(acc[j], 32);
  }
  if (g == 0) {
    const float4 c0 = *(const float4*)&bs1[fl * 8];
    const float4 c1 = *(const float4*)&bs1[fl * 8 + 4];
    unsigned short o[8];
    o[0] = f2bf(fmaxf(acc[0] + c0.x, 0.f));
    o[1] = f2bf(fmaxf(acc[1] + c0.y, 0.f));
    o[2] = f2bf(fmaxf(acc[2] + c0.z, 0.f));
    o[3] = f2bf(fmaxf(acc[3] + c0.w, 0.f));
    o[4] = f2bf(fmaxf(acc[4] + c1.x, 0.f));
    o[5] = f2bf(fmaxf(acc[5] + c1.y, 0.f));
    o[6] = f2bf(fmaxf(acc[6] + c1.z, 0.f));
    o[7] = f2bf(fmaxf(acc[7] + c1.w, 0.f));
    *(bf16x8*)&h1b[(size_t)node * 128 + fl * 8] = *(bf16x8*)o;
  }
}

// gather2: 1 node/wave; 8 edge-groups x 8 lanes; lane holds 8 features; f32 out (F=64).
__global__ __launch_bounds__(256) void gather2_k(const unsigned short* __restrict__ H,
                                                 const int* __restrict__ row_ptr,
                                                 const int2* __restrict__ csr,
                                                 const float* __restrict__ bs2,
                                                 float* __restrict__ out) {
  const int node = blockIdx.x * 4 + (threadIdx.x >> 6);
  const int lane = threadIdx.x & 63;
  if (node >= NN) return;
  const int g  = lane >> 3;   // edge slot 0..7
  const int fl = lane & 7;    // feature chunk (8 bf16)

  float acc[8];
#pragma unroll
  for (int j = 0; j < 8; ++j) acc[j] = 0.f;

  const int beg = row_ptr[node];
  const int end = row_ptr[node + 1];
  for (int e = beg + g; e < end; e += 8) {
    const int2 p = csr[e];
    const float w = __int_as_float(p.y);
    const bf16x8 h = *(const bf16x8*)&H[(size_t)p.x * 64 + fl * 8];
#pragma unroll
    for (int j = 0; j < 8; ++j)
      acc[j] = fmaf(bf2f((unsigned short)h[j]), w, acc[j]);
  }
#pragma unroll
  for (int j = 0; j < 8; ++j) {
    acc[j] += __shfl_xor(acc[j], 8);
    acc[j] += __shfl_xor(acc[j], 16);
    acc[j] += __shfl_xor(acc[j], 32);
  }
  if (g == 0) {
    const float4 c0 = *(const float4*)&bs2[fl * 8];
    const float4 c1 = *(const float4*)&bs2[fl * 8 + 4];
    float4 o0, o1;
    o0.x = acc[0] + c0.x; o0.y = acc[1] + c0.y; o0.z = acc[2] + c0.z; o0.w = acc[3] + c0.w;
    o1.x = acc[4] + c1.x; o1.y = acc[5] + c1.y; o1.z = acc[6] + c1.z; o1.w = acc[7] + c1.w;
    *(float4*)&out[(size_t)node * 64 + fl * 8]     = o0;
    *(float4*)&out[(size_t)node * 64 + fl * 8 + 4] = o1;
  }
}

// ---------------------------------------------------------------- launch
extern "C" void kernel_launch(void* const* d_in, const int* in_sizes, int n_in,
                              void* d_out, int out_size, void* d_ws, size_t ws_size,
                              hipStream_t stream) {
  const float* x     = (const float*)d_in[0];
  const int*   edges = (const int*)d_in[1];
  const float* W1    = (const float*)d_in[2];
  const float* b1    = (const float*)d_in[3];
  const float* W2    = (const float*)d_in[4];
  const float* b2    = (const float*)d_in[5];
  float* out = (float*)d_out;

  // ---- workspace layout
  unsigned short* xb   = (unsigned short*)d_ws;            // NN*128 bf16
  unsigned short* h1b  = xb;                               // reuse after layer1 GEMM
  unsigned short* Hbuf = xb + (size_t)NN * 128;            // NR*NN*128 bf16
  unsigned short* Wt1  = Hbuf + (size_t)NR * NN * 128;     // NR*128*128 bf16
  unsigned short* Wt2  = Wt1 + (size_t)NR * 128 * 128;     // NR*64*128 bf16
  float* rs_out = (float*)(Wt2 + (size_t)NR * 64 * 128);   // NR*NN
  float* rs_in  = rs_out + (size_t)NR * NN;                // NR*NN
  int* cnt_out  = (int*)(rs_in + (size_t)NR * NN);         // NR*NN
  int* cnt_in   = cnt_out + (size_t)NR * NN;               // NR*NN
  int* row_ptr  = cnt_in + (size_t)NR * NN;                // NN+1
  int* cursor   = row_ptr + (NN + 1);                      // NN
  int* bsum     = cursor + NN;                             // 128
  float* bs1    = (float*)(bsum + 128);                    // 128
  float* bs2    = bs1 + 128;                               // 64
  int2* csr     = (int2*)(bs2 + 64);                       // NR*NE int2

  const int nb = (NN + SCAN_B - 1) / SCAN_B;  // 98

  // ---- degrees + combined CSR
  hipMemsetAsync(cnt_out, 0, (size_t)2 * NR * NN * sizeof(int), stream);
  count_k<<<dim3((NE + 255) / 256, NR), 256, 0, stream>>>(edges, cnt_out, cnt_in);
  rs_k<<<(2 * NR * NN + 255) / 256, 256, 0, stream>>>(cnt_out, rs_out, 2 * NR * NN);
  scan1_k<<<nb, 256, 0, stream>>>(cnt_in, cursor /*excl temp*/, bsum);
  scan2_k<<<1, 128, 0, stream>>>(bsum, nb);
  scan3_k<<<(NN + 255) / 256, 256, 0, stream>>>(cursor, bsum, row_ptr, cursor);
  fill_k<<<dim3((NE + 255) / 256, NR), 256, 0, stream>>>(edges, rs_in, cursor, csr);
  bias_sum_k<<<1, 128, 0, stream>>>(b1, b2, bs1, bs2);

  // ---- bf16 conversions
  cvtx_k<<<((NN * 128 / 8) + 255) / 256, 256, 0, stream>>>(x, xb, NN * 128 / 8);
  cvtw_k<<<(NR * 128 * 128 + 255) / 256, 256, 0, stream>>>(W1, Wt1, 128, NR * 128 * 128);
  cvtw_k<<<(NR * 128 * 64 + 255) / 256, 256, 0, stream>>>(W2, Wt2, 64, NR * 128 * 64);

  const int ntiles = (NN + 127) / 128;  // 782

  // ---- layer 1
  gemm2_k<128><<<dim3(128, 1, NR), 256, 0, stream>>>(xb, Wt1, rs_out, Hbuf, NN, ntiles);
  gather1_k<<<(NN + 3) / 4, 256, 0, stream>>>(Hbuf, row_ptr, csr, bs1, h1b);

  // ---- layer 2
  gemm2_k<64><<<dim3(128, 1, NR), 256, 0, stream>>>(h1b, Wt2, rs_out, Hbuf, NN, ntiles);
  gather2_k<<<(NN + 3) / 4, 256, 0, stream>>>(Hbuf, row_ptr, csr, bs2, out);
}